// Round 2
// baseline (2172.674 us; speedup 1.0000x reference)
//
#include <hip/hip_runtime.h>
#include <stdint.h>

// TreeRNN: T=256 steps, D=512 rows, H=E=256, V=8192.
// 256 blocks (16 row-groups x 16 col-slices), PLAIN launch (capacity arithmetic:
// launch_bounds(256,1) => >=1 block/CU schedulable; grid=256=#CUs => all blocks
// resident; per-group counter sync cannot starve). Each block owns rows[32] x
// cols[16]; weight slices live in VGPRs as MFMA B-fragments (192 VGPR/wave).
// Per step: ih-GEMM on prefetched x -> poll group counter -> gather h_t (fp32,
// agent-scope) -> hh-GEMM -> gates (fp32 carry in LDS) -> publish h_{t+1} via
// agent-scope stores + relaxed fetch_add after the barrier's vmcnt drain.
// Input dtypes (fp32 vs bf16 floats; u8/i32/f32/bf16 edges) detected at runtime.

#define TT   256
#define DDIM 512
#define LSTR 264   // LDS row stride in bf16 elems (256 + 8 pad)

typedef float    float4v __attribute__((ext_vector_type(4)));
typedef short    short8  __attribute__((ext_vector_type(8)));
typedef uint32_t uint4v  __attribute__((ext_vector_type(4)));

__device__ __forceinline__ unsigned short f2bf(float f){
  uint32_t u = __float_as_uint(f);
  u += 0x7fffu + ((u >> 16) & 1u);          // RNE, finite inputs
  return (unsigned short)(u >> 16);
}
__device__ __forceinline__ float bf2f(unsigned short h){
  return __uint_as_float(((uint32_t)h) << 16);
}

__global__ __launch_bounds__(256, 1)
void treernn_main(const int* __restrict__ nodes,
                  const unsigned char* __restrict__ edges,
                  const unsigned char* __restrict__ hinit,
                  const unsigned char* __restrict__ emb,
                  const unsigned char* __restrict__ cWih, const unsigned char* __restrict__ cWhh,
                  const unsigned char* __restrict__ cbih, const unsigned char* __restrict__ cbhh,
                  const unsigned char* __restrict__ sWih, const unsigned char* __restrict__ sWhh,
                  const unsigned char* __restrict__ sbih, const unsigned char* __restrict__ sbhh,
                  unsigned char* __restrict__ out,
                  unsigned char* __restrict__ ws)
{
  __shared__ __align__(16) unsigned short xs[2][32 * LSTR];  // x tiles (bf16), dbuf
  __shared__ __align__(16) unsigned short hstg[32 * LSTR];   // h_t (bf16) for MFMA A
  __shared__ float hnewstg[32 * 17];                         // fp32 state carry (own slice)
  __shared__ int det[8];

  const int tid   = threadIdx.x;
  const int lane  = tid & 63;
  const int wv    = tid >> 6;
  const int gru   = wv >> 1;        // 0 = child GRU, 1 = sibling GRU
  const int mtile = wv & 1;         // 16-row half of the 32-row group
  const int quad  = lane >> 4;
  const int l16   = lane & 15;

  const int g     = blockIdx.x >> 4;        // rows [g*32, g*32+32)
  const int slice = blockIdx.x & 15;        // cols [slice*16, +16)
  const int col   = slice * 16 + l16;
  const int d0    = g * 32;
  const int rowb  = mtile * 16 + quad * 4;  // C/D layout: row = quad*4 + reg

  // ---------------- runtime dtype detection (deterministic, per-block) ----------------
  if (tid < 8) det[tid] = 0;
  __syncthreads();
  {
    const unsigned short* hu = (const unsigned short*)hinit;
    int ce = 0;
    for (int i = tid; i < 4096; i += 256){
      const int e = (hu[i] >> 7) & 0xFF;          // bf16 exponent field
      ce += (e >= 100 && e <= 130) ? 1 : 0;       // |v| in [2^-27, 2^4)
    }
    atomicAdd(&det[0], ce);
    const uint32_t* ewp = (const uint32_t*)edges;
    int b01 = 0, w01 = 0, wf = 0, hb = 0;
    for (int i = tid; i < 512; i += 256){
      const uint32_t w = ewp[i];
      w01 += (w <= 1u) ? 1 : 0;
      wf  += (w == 0u || w == 0x3F800000u) ? 1 : 0;
      const uint32_t h0 = w & 0xFFFFu, h1 = w >> 16;
      hb  += ((h0 == 0u || h0 == 0x3F80u) ? 1 : 0) + ((h1 == 0u || h1 == 0x3F80u) ? 1 : 0);
      b01 += (((w      ) & 0xFFu) <= 1u ? 1 : 0) + (((w >> 8 ) & 0xFFu) <= 1u ? 1 : 0)
           + (((w >> 16) & 0xFFu) <= 1u ? 1 : 0) + (((w >> 24)        ) <= 1u ? 1 : 0);
    }
    atomicAdd(&det[1], b01); atomicAdd(&det[2], w01);
    atomicAdd(&det[3], wf);  atomicAdd(&det[4], hb);
  }
  __syncthreads();
  const int fdt = (det[0] >= 3480) ? 1 : 0;   // bf16 ~4096, fp32 ~2300
  int efmt;                                    // 0=u8, 1=i32, 2=f32, 3=bf16
  if      (det[2] == 512)  efmt = 1;
  else if (det[1] == 2048) efmt = 0;
  else if (det[4] == 1024) efmt = 3;
  else if (det[3] == 512)  efmt = 2;
  else                     efmt = 0;

  uint32_t* ctr = (uint32_t*)(ws + 128 + g * 128);
  uint32_t* xb  = (uint32_t*)(ws + 8192);     // exchange: [2][512][256] fp32 bits

  const unsigned char* Wihp = gru ? sWih : cWih;
  const unsigned char* Whhp = gru ? sWhh : cWhh;
  const unsigned char* bihp = gru ? sbih : cbih;
  const unsigned char* bhhp = gru ? sbhh : cbhh;

  float bI[3], bH[3];
  #pragma unroll
  for (int ga = 0; ga < 3; ++ga){
    if (fdt){
      bI[ga] = bf2f(((const unsigned short*)bihp)[ga * 256 + col]);
      bH[ga] = bf2f(((const unsigned short*)bhhp)[ga * 256 + col]);
    } else {
      bI[ga] = ((const float*)bihp)[ga * 256 + col];
      bH[ga] = ((const float*)bhhp)[ga * 256 + col];
    }
  }

  // One-time: weight slices -> bf16 MFMA B-fragments in registers.
  // B-frag (16x16x32): lane holds B[k = quad*8 + j][n = l16] = W[n-row][k] (row-major).
  short8 wI[3][8], wH[3][8];
  for (int ga = 0; ga < 3; ++ga){
    const int rw = ga * 256 + col;
    for (int kc = 0; kc < 8; ++kc){
      const int ke = kc * 32 + quad * 8;
      if (fdt){
        wI[ga][kc] = *(const short8*)((const unsigned short*)Wihp + (size_t)rw * 256 + ke);
        wH[ga][kc] = *(const short8*)((const unsigned short*)Whhp + (size_t)rw * 256 + ke);
      } else {
        const float* pI = (const float*)Wihp + (size_t)rw * 256 + ke;
        const float* pH = (const float*)Whhp + (size_t)rw * 256 + ke;
        short8 va, vb;
        #pragma unroll
        for (int j = 0; j < 8; ++j){ va[j] = (short)f2bf(pI[j]); vb[j] = (short)f2bf(pH[j]); }
        wI[ga][kc] = va; wH[ga][kc] = vb;
      }
    }
  }

  // Stage x_0 and h_0: thread -> row tid>>3, 32 cols from (tid&7)*32
  {
    const int r = tid >> 3, c8 = (tid & 7) * 32;
    const int node = nodes[d0 + r];
    unsigned short* xdst = &xs[0][r * LSTR + c8];
    unsigned short* hdst = &hstg[r * LSTR + c8];
    if (fdt){
      const uint4v* sx = (const uint4v*)((const unsigned short*)emb   + (size_t)node * 256 + c8);
      const uint4v* sh = (const uint4v*)((const unsigned short*)hinit + (size_t)(d0 + r) * 256 + c8);
      #pragma unroll
      for (int j = 0; j < 4; ++j){ ((uint4v*)xdst)[j] = sx[j]; ((uint4v*)hdst)[j] = sh[j]; }
    } else {
      const float* sx = (const float*)emb   + (size_t)node * 256 + c8;
      const float* sh = (const float*)hinit + (size_t)(d0 + r) * 256 + c8;
      #pragma unroll
      for (int q = 0; q < 4; ++q){
        short8 vx, vh;
        #pragma unroll
        for (int j = 0; j < 8; ++j){ vx[j] = (short)f2bf(sx[q*8+j]); vh[j] = (short)f2bf(sh[q*8+j]); }
        *(short8*)&xdst[q * 8] = vx;
        *(short8*)&hdst[q * 8] = vh;
      }
    }
  }
  __syncthreads();

  for (int t = 0; t < TT; ++t){
    // ---- ih-GEMM on staged x_t (peer-independent: overlaps the wait) ----
    float4v aI[3], aH[3];
    #pragma unroll
    for (int ga = 0; ga < 3; ++ga) aI[ga] = (float4v){bI[ga], bI[ga], bI[ga], bI[ga]};
    {
      const unsigned short* xc = xs[t & 1];
      #pragma unroll
      for (int kc = 0; kc < 8; ++kc){
        // A-frag: lane holds A[m = l16][k = quad*8 + j]
        short8 a = *(const short8*)&xc[(mtile * 16 + l16) * LSTR + kc * 32 + quad * 8];
        #pragma unroll
        for (int ga = 0; ga < 3; ++ga)
          aI[ga] = __builtin_amdgcn_mfma_f32_16x16x32_bf16(a, wI[ga][kc], aI[ga], 0, 0, 0);
      }
    }

    // ---- edges for this step ----
    int ef[4];
    {
      const int base = t * DDIM + d0 + rowb;
      if (efmt == 0){      for (int r = 0; r < 4; ++r) ef[r] = edges[base + r] != 0; }
      else if (efmt == 1){ for (int r = 0; r < 4; ++r) ef[r] = ((const int*)edges)[base + r] != 0; }
      else if (efmt == 3){ for (int r = 0; r < 4; ++r) ef[r] = ((const unsigned short*)edges)[base + r] != 0; }
      else {               for (int r = 0; r < 4; ++r) ef[r] = ((const float*)edges)[base + r] != 0.0f; }
    }

    // ---- gather h_t (t>0): poll group counter, then agent-scope loads ----
    if (t > 0){
      if (lane == 0){
        const uint32_t target = 16u * (uint32_t)t;
        int guard = 0;
        while (__hip_atomic_load(ctr, __ATOMIC_RELAXED, __HIP_MEMORY_SCOPE_AGENT) < target){
          __builtin_amdgcn_s_sleep(2);
          if (++guard > (1 << 15)) break;   // bounded: broken sync -> garbage, not hang
        }
      }
      __atomic_signal_fence(__ATOMIC_SEQ_CST);
      const int r = tid >> 3;
      const uint64_t* src = (const uint64_t*)(xb + (size_t)(t & 1) * 131072
                                                 + (size_t)(d0 + r) * 256) + (tid & 7) * 16;
      uint64_t gv[16];
      #pragma unroll
      for (int k = 0; k < 16; ++k)
        gv[k] = __hip_atomic_load(src + k, __ATOMIC_RELAXED, __HIP_MEMORY_SCOPE_AGENT);
      unsigned short* dst = &hstg[r * LSTR + (tid & 7) * 32];
      #pragma unroll
      for (int q = 0; q < 4; ++q){
        short8 v;
        #pragma unroll
        for (int j = 0; j < 8; ++j){
          const int e2 = q * 8 + j;
          const uint32_t uw = (uint32_t)(gv[e2 >> 1] >> ((e2 & 1) * 32));
          v[j] = (short)f2bf(__uint_as_float(uw));
        }
        *(short8*)&dst[q * 8] = v;
      }
    }
    __syncthreads();   // hstg ready

    // ---- fp32 state carry (own 16-col slice) ----
    float hold[4];
    if (t == 0){
      #pragma unroll
      for (int r = 0; r < 4; ++r){
        const size_t idx = (size_t)(d0 + rowb + r) * 256 + col;
        hold[r] = fdt ? bf2f(((const unsigned short*)hinit)[idx]) : ((const float*)hinit)[idx];
      }
    } else {
      #pragma unroll
      for (int r = 0; r < 4; ++r) hold[r] = hnewstg[(rowb + r) * 17 + l16];
    }

    // ---- hh-GEMM ----
    #pragma unroll
    for (int ga = 0; ga < 3; ++ga) aH[ga] = (float4v){bH[ga], bH[ga], bH[ga], bH[ga]};
    #pragma unroll
    for (int kc = 0; kc < 8; ++kc){
      short8 a = *(const short8*)&hstg[(mtile * 16 + l16) * LSTR + kc * 32 + quad * 8];
      #pragma unroll
      for (int ga = 0; ga < 3; ++ga)
        aH[ga] = __builtin_amdgcn_mfma_f32_16x16x32_bf16(a, wH[ga][kc], aH[ga], 0, 0, 0);
    }

    // ---- prefetch x_{t+1} raw (cvt after barrier) ----
    uint4v rv[8];
    if (t < TT - 1){
      const int r = tid >> 3, c8 = (tid & 7) * 32;
      const int node = nodes[(t + 1) * DDIM + d0 + r];
      if (fdt){
        const uint4v* s = (const uint4v*)((const unsigned short*)emb + (size_t)node * 256 + c8);
        #pragma unroll
        for (int j = 0; j < 4; ++j) rv[j] = s[j];
      } else {
        const uint4v* s = (const uint4v*)((const float*)emb + (size_t)node * 256 + c8);
        #pragma unroll
        for (int j = 0; j < 8; ++j) rv[j] = s[j];
      }
    }

    __syncthreads();   // hold reads done before hnewstg overwrite

    // ---- gates: r=sig(ir+hr), z=sig(iz+hz), n=tanh(in + r*hn); h' = (1-z)n + z h ----
    float hnv[4]; int mine[4];
    #pragma unroll
    for (int r = 0; r < 4; ++r){
      const float pr = aI[0][r] + aH[0][r];
      const float pz = aI[1][r] + aH[1][r];
      const float R  = 1.0f / (1.0f + exp2f(-1.4426950408889634f * pr));
      const float Z  = 1.0f / (1.0f + exp2f(-1.4426950408889634f * pz));
      float ag = aI[2][r] + R * aH[2][r];
      ag = fminf(30.0f, fmaxf(-30.0f, ag));
      const float ex = exp2f(-2.8853900817779268f * ag);
      const float N  = (1.0f - ex) / (1.0f + ex);
      hnv[r]  = N + Z * (hold[r] - N);
      mine[r] = ((ef[r] != 0) == (gru == 0)) ? 1 : 0;   // edge -> child GRU
    }

    // ---- local carry + publish h_{t+1} (per-lane fp32, agent-scope bypass) ----
    #pragma unroll
    for (int r = 0; r < 4; ++r){
      if (mine[r]){
        hnewstg[(rowb + r) * 17 + l16] = hnv[r];
        if (t < TT - 1)
          __hip_atomic_store(xb + (size_t)((t + 1) & 1) * 131072
                                + (size_t)(d0 + rowb + r) * 256 + col,
                             __float_as_uint(hnv[r]),
                             __ATOMIC_RELAXED, __HIP_MEMORY_SCOPE_AGENT);
      }
    }

    // ---- stage x_{t+1} ----
    if (t < TT - 1){
      unsigned short* dst = &xs[(t + 1) & 1][(tid >> 3) * LSTR + (tid & 7) * 32];
      if (fdt){
        #pragma unroll
        for (int j = 0; j < 4; ++j) ((uint4v*)dst)[j] = rv[j];
      } else {
        #pragma unroll
        for (int q = 0; q < 4; ++q){
          short8 v;
          #pragma unroll
          for (int j = 0; j < 8; ++j){
            const int e2 = q * 8 + j;
            v[j] = (short)f2bf(__uint_as_float(rv[e2 >> 2][e2 & 3]));
          }
          *(short8*)&dst[q * 8] = v;
        }
      }
    }

    __syncthreads();   // drains vmcnt: exchange stores complete at coherent point

    if (tid == 0)
      __hip_atomic_fetch_add(ctr, 1u, __ATOMIC_RELAXED, __HIP_MEMORY_SCOPE_AGENT);

    // ---- outputs (off critical path): outs[t] and dup of outs[T-1] as h_final ----
    #pragma unroll
    for (int r = 0; r < 4; ++r){
      if (mine[r]){
        const size_t oi = (size_t)t  * 131072 + (size_t)(d0 + rowb + r) * 256 + col;
        const size_t fi = (size_t)TT * 131072 + (size_t)(d0 + rowb + r) * 256 + col;
        if (fdt){
          const unsigned short h16 = f2bf(hnv[r]);
          __builtin_nontemporal_store(h16, (unsigned short*)out + oi);
          if (t == TT - 1) __builtin_nontemporal_store(h16, (unsigned short*)out + fi);
        } else {
          __builtin_nontemporal_store(hnv[r], (float*)out + oi);
          if (t == TT - 1) __builtin_nontemporal_store(hnv[r], (float*)out + fi);
        }
      }
    }
  }
}

extern "C" void kernel_launch(void* const* d_in, const int* in_sizes, int n_in,
                              void* d_out, int out_size, void* d_ws, size_t ws_size,
                              hipStream_t stream)
{
  const int*           nodes = (const int*)d_in[0];
  const unsigned char* edges = (const unsigned char*)d_in[1];
  const unsigned char* hinit = (const unsigned char*)d_in[2];
  const unsigned char* emb   = (const unsigned char*)d_in[3];
  const unsigned char* cWih  = (const unsigned char*)d_in[4];
  const unsigned char* cWhh  = (const unsigned char*)d_in[5];
  const unsigned char* cbih  = (const unsigned char*)d_in[6];
  const unsigned char* cbhh  = (const unsigned char*)d_in[7];
  const unsigned char* sWih  = (const unsigned char*)d_in[8];
  const unsigned char* sWhh  = (const unsigned char*)d_in[9];
  const unsigned char* sbih  = (const unsigned char*)d_in[10];
  const unsigned char* sbhh  = (const unsigned char*)d_in[11];
  (void)in_sizes; (void)n_in; (void)out_size; (void)ws_size;

  // zero flag/counter region (ws re-poisoned 0xAA before every launch)
  hipMemsetAsync(d_ws, 0, 8192, stream);

  treernn_main<<<dim3(256), dim3(256), 0, stream>>>(
      nodes, edges, hinit, emb, cWih, cWhh, cbih, cbhh, sWih, sWhh, sbih, sbhh,
      (unsigned char*)d_out, (unsigned char*)d_ws);
}